// Round 10
// baseline (422.968 us; speedup 1.0000x reference)
//
#include <hip/hip_runtime.h>
#include <stdint.h>

typedef __bf16 bf16x8 __attribute__((ext_vector_type(8)));
typedef float f32x4 __attribute__((ext_vector_type(4)));
typedef unsigned short ushort8v __attribute__((ext_vector_type(8)));

__device__ __forceinline__ void gload_lds16(const void* g, void* l) {
  __builtin_amdgcn_global_load_lds(
      (const __attribute__((address_space(1))) void*)g,
      (__attribute__((address_space(3))) void*)l, 16, 0, 0);
}

__device__ __forceinline__ unsigned short f2bf(float f) {
  union { float f; unsigned int u; } x; x.f = f;
  unsigned int r = x.u + 0x7FFFu + ((x.u >> 16) & 1u);
  return (unsigned short)(r >> 16);
}

__device__ __forceinline__ float ftanh(float x) {
  float ax = fabsf(x);
  float e = __expf(-2.0f * ax);
  float r = (1.0f - e) / (1.0f + e);
  return copysignf(r, x);
}

// -------- W1 f32 -> bf16, PRE-SWIZZLED 16 KB chunk layout --------
// chunk p = (aq*8 + k8)*4 + c8 covers a in [aq*256 + c8*64, +64),
// k in [k8*128, +128). Within a chunk (64 rows x 256 B), dest byte d
// holds source k-byte (d&255) ^ ((row&15)<<4), row = d>>8 (inverse of
// the read swizzle): LINEAR global->LDS copy + swizzled read works.
__global__ __launch_bounds__(256) void w1cvt_kernel(
    const float* __restrict__ W1, unsigned short* __restrict__ w1b) {
  const int g = blockIdx.x * 256 + threadIdx.x; /* 16-B piece id */
  const int p = g >> 10;
  const int q = g & 1023;
  const int row = q >> 4;
  const int off = (q & 15) * 16;
  const int srcoff = off ^ ((row & 15) << 4);
  const int c8 = p & 3, k8 = (p >> 2) & 7, aq = p >> 5;
  const int a = aq * 256 + c8 * 64 + row;
  const int k = k8 * 128 + (srcoff >> 1);
  const float* src = W1 + (size_t)a * 1024 + k;
  const float4 v0 = *(const float4*)src;
  const float4 v1 = *(const float4*)(src + 4);
  ushort8v o;
  o[0] = f2bf(v0.x); o[1] = f2bf(v0.y); o[2] = f2bf(v0.z); o[3] = f2bf(v0.w);
  o[4] = f2bf(v1.x); o[5] = f2bf(v1.y); o[6] = f2bf(v1.z); o[7] = f2bf(v1.w);
  *((ushort8v*)w1b + g) = o;
}

// ---------------- u[b][a] = sum_d dec[b][d] * W2[a][d] ----------------
__global__ __launch_bounds__(256) void dec_proj_kernel(
    const float* __restrict__ dec, const float* __restrict__ W2,
    float* __restrict__ u) {
  __shared__ __align__(16) float w2s[1024];
  const int a = blockIdx.x;
  const int t = threadIdx.x;
  *(float4*)(w2s + t * 4) = *(const float4*)(W2 + (size_t)a * 1024 + t * 4);
  __syncthreads();
  const int wid = t >> 6, l = t & 63;
  for (int bi = 0; bi < 8; ++bi) {
    const int b = wid * 8 + bi;
    const float* dp = dec + (size_t)b * 1024;
    float acc = 0.f;
#pragma unroll
    for (int i = 0; i < 4; ++i) {
      const int k = i * 256 + l * 4;
      const float4 dv = *(const float4*)(dp + k);
      const float4 wv = *(const float4*)(w2s + k);
      acc = fmaf(dv.x, wv.x, acc); acc = fmaf(dv.y, wv.y, acc);
      acc = fmaf(dv.z, wv.z, acc); acc = fmaf(dv.w, wv.w, acc);
    }
#pragma unroll
    for (int m = 1; m < 64; m <<= 1) acc += __shfl_xor(acc, m, 64);
    if (l == 0) u[(size_t)b * 1024 + a] = acc;
  }
}

// ---------------- fused partial scores: v . tanh(enc@W1^T + u) ----------
// grid 4096: (row-tile rt = bid>>2) x (a-quarter aq = bid&3).
// Block: 64 rows x 256 a-cols x full K. A-frags cached in regs per k8
// (af[2][4], read 8x per k8); B 16KB chunks, 3-buf counted-vmcnt staging
// (R9-verified schedule). acc[4][2] = 32 AGPR. ~128 regs -> 2 blocks/CU.
// Partial v-weighted sums -> spart[aq][65536]; softmax adds the 4.
__global__ __launch_bounds__(512, 4) void scores_kernel(
    const float* __restrict__ enc, const unsigned short* __restrict__ w1b,
    const float* __restrict__ u, const float* __restrict__ vvec,
    float* __restrict__ spart) {
  __shared__ __align__(16) char encL[16384];
  __shared__ __align__(16) char Bl[49152];
  __shared__ __align__(16) float sred[256];

  const int t = threadIdx.x;
  const int bid = blockIdx.x;
  const int rt = bid >> 2, aq = bid & 3;
  const int m0 = rt * 64;
  const int b = rt >> 5; /* 32 row-tiles per batch */
  const int l = t & 63, wid = t >> 6;
  const int wr = wid >> 2, wc = wid & 3;
  const int lm = l & 15, lg = l >> 4;

  const int row_a0 = wr * 32 + lm; /* rowfrag1 = +16: same (row&15) bits */
  const int aswz = lm << 4;
  const int abase0 = row_a0 * 256;        /* enc row stride 256 B */
  const int bbase = (wc * 16 + lm) * 256; /* B row stride 256 B */
  const int bswz = lm << 4;
  const char* w1c = (const char*)w1b;
  const char* base = w1c + (size_t)aq * 524288; /* this quarter: 32 chunks */
  const float* ub = u + (size_t)b * 1024;

  const int sbase0 = wid * 2048;
  const int sbase1 = wid * 2048 + 1024;
  const int glane = l * 16;

  f32x4 rowp0 = {0.f, 0.f, 0.f, 0.f}, rowp1 = {0.f, 0.f, 0.f, 0.f};

  // prologue: stage chunk 0 -> buf0, chunk 1 -> buf1 (outstanding = 4)
  gload_lds16(base + sbase0 + glane, Bl + sbase0);
  gload_lds16(base + sbase1 + glane, Bl + sbase1);
  gload_lds16(base + 16384 + sbase0 + glane, Bl + 16384 + sbase0);
  gload_lds16(base + 16384 + sbase1 + glane, Bl + 16384 + sbase1);

  const char* nextsrc = base + 2 * 16384; /* chunk p+2 source, wraps */
  int bsel = 0; /* current buf = p%3 */
  int nb = 2;   /* buf for p+2 */

  f32x4 acc[4][2];
#pragma unroll
  for (int c1 = 0; c1 < 4; ++c1)
#pragma unroll
    for (int c2 = 0; c2 < 2; ++c2) acc[c1][c2] = (f32x4){0.f, 0.f, 0.f, 0.f};

  for (int k8 = 0; k8 < 8; ++k8) {
    bf16x8 af[2][4];
#pragma unroll
    for (int c8 = 0; c8 < 4; ++c8) {
      // ---- phase top: own stage(p) retired; all waves aligned ----
      asm volatile("s_waitcnt vmcnt(2)" ::: "memory");
      __builtin_amdgcn_s_barrier();
      // ---- issue stage(p+2) into the third buffer ----
      gload_lds16(nextsrc + sbase0 + glane, Bl + nb * 16384 + sbase0);
      gload_lds16(nextsrc + sbase1 + glane, Bl + nb * 16384 + sbase1);
      nextsrc += 16384;
      if (nextsrc == base + 524288) nextsrc = base; /* tail dummies wrap */
      if (c8 == 0) {
        // ---- stage enc eighth: 64 rows x 128 k, f32 -> bf16 ----
#pragma unroll
        for (int it = 0; it < 2; ++it) {
          const int c = it * 512 + t;
          const int row = c >> 4;
          const int k0 = (c & 15) * 8;
          const float* g = enc + (size_t)(m0 + row) * 1024 + k8 * 128 + k0;
          const float4 v0 = *(const float4*)g;
          const float4 v1 = *(const float4*)(g + 4);
          ushort8v o;
          o[0] = f2bf(v0.x); o[1] = f2bf(v0.y); o[2] = f2bf(v0.z); o[3] = f2bf(v0.w);
          o[4] = f2bf(v1.x); o[5] = f2bf(v1.y); o[6] = f2bf(v1.z); o[7] = f2bf(v1.w);
          const int dest = row * 256 + ((k0 * 2) ^ ((row & 15) << 4));
          *(ushort8v*)(encL + dest) = o;
        }
        __syncthreads(); /* encL visible (staged B lands too) */
        // ---- A-fragments into registers: 8 ds_read_b128 per k8 ----
#pragma unroll
        for (int rf = 0; rf < 2; ++rf)
#pragma unroll
          for (int kk = 0; kk < 4; ++kk)
            af[rf][kk] = *(const bf16x8*)(encL + abase0 + rf * 4096 +
                                          ((kk * 64 + lg * 16) ^ aswz));
      }
      // ---- compute phase p from buf bsel: 4 B-reads + 8 MFMA ----
      const int cbuf = bsel * 16384;
      __builtin_amdgcn_s_setprio(1);
#pragma unroll
      for (int kk = 0; kk < 4; ++kk) {
        const bf16x8 b0 = *(const bf16x8*)(Bl + cbuf + bbase +
                                           ((kk * 64 + lg * 16) ^ bswz));
        acc[c8][0] = __builtin_amdgcn_mfma_f32_16x16x32_bf16(af[0][kk], b0, acc[c8][0], 0, 0, 0);
        acc[c8][1] = __builtin_amdgcn_mfma_f32_16x16x32_bf16(af[1][kk], b0, acc[c8][1], 0, 0, 0);
      }
      __builtin_amdgcn_s_setprio(0);
      bsel = (bsel + 1 == 3) ? 0 : bsel + 1;
      nb = (nb + 1 == 3) ? 0 : nb + 1;
    }
  }

  // epilogue: tanh + v-weighted column reduction (full K done)
#pragma unroll
  for (int c8 = 0; c8 < 4; ++c8) {
    const int colA = aq * 256 + c8 * 64 + wc * 16 + lm;
    const float uu = ub[colA], vv = vvec[colA];
#pragma unroll
    for (int j = 0; j < 4; ++j) {
      rowp0[j] += ftanh(acc[c8][0][j] + uu) * vv;
      rowp1[j] += ftanh(acc[c8][1][j] + uu) * vv;
    }
  }

  // reduce over the 16 col-lanes (lm) of each fragment group
#pragma unroll
  for (int m = 1; m < 16; m <<= 1) {
#pragma unroll
    for (int j = 0; j < 4; ++j) {
      rowp0[j] += __shfl_xor(rowp0[j], m, 64);
      rowp1[j] += __shfl_xor(rowp1[j], m, 64);
    }
  }
  if (lm == 0) {
#pragma unroll
    for (int j = 0; j < 4; ++j) {
      sred[wc * 64 + wr * 32 + lg * 4 + j] = rowp0[j];
      sred[wc * 64 + wr * 32 + 16 + lg * 4 + j] = rowp1[j];
    }
  }
  __syncthreads();
  if (t < 64) {
    spart[aq * 65536 + m0 + t] =
        sred[t] + sred[64 + t] + sred[128 + t] + sred[192 + t];
  }
}

// -------- masked softmax over L: sums 4 partials, writes attn ----------
__global__ __launch_bounds__(256) void softmax_kernel(
    const float* __restrict__ spart, float* __restrict__ out,
    const int* __restrict__ mask) {
  __shared__ float wred[4];
  const int bidx = blockIdx.x;
  const int t = threadIdx.x;
  const int r8 = bidx * 2048 + t * 8;
  float* at = out + 32768 + (size_t)bidx * 2048;
  const int* mk = mask + (size_t)bidx * 2048;
  float v[8] = {0.f, 0.f, 0.f, 0.f, 0.f, 0.f, 0.f, 0.f};
#pragma unroll
  for (int aq = 0; aq < 4; ++aq) {
    const float4 s0 = *(const float4*)(spart + aq * 65536 + r8);
    const float4 s1 = *(const float4*)(spart + aq * 65536 + r8 + 4);
    v[0] += s0.x; v[1] += s0.y; v[2] += s0.z; v[3] += s0.w;
    v[4] += s1.x; v[5] += s1.y; v[6] += s1.z; v[7] += s1.w;
  }
  const int4 q0 = *(const int4*)(mk + t * 8);
  const int4 q1 = *(const int4*)(mk + t * 8 + 4);
  int q[8] = {q0.x, q0.y, q0.z, q0.w, q1.x, q1.y, q1.z, q1.w};
  float mx = -3.0e38f;
#pragma unroll
  for (int j = 0; j < 8; ++j) if (q[j] != 0) mx = fmaxf(mx, v[j]);
#pragma unroll
  for (int m = 1; m < 64; m <<= 1) mx = fmaxf(mx, __shfl_xor(mx, m, 64));
  if ((t & 63) == 0) wred[t >> 6] = mx;
  __syncthreads();
  mx = fmaxf(fmaxf(wred[0], wred[1]), fmaxf(wred[2], wred[3]));
  __syncthreads();
  float pp[8]; float sum = 0.f;
#pragma unroll
  for (int j = 0; j < 8; ++j) {
    pp[j] = (q[j] != 0) ? __expf(v[j] - mx) : 0.f;
    sum += pp[j];
  }
#pragma unroll
  for (int m = 1; m < 64; m <<= 1) sum += __shfl_xor(sum, m, 64);
  if ((t & 63) == 0) wred[t >> 6] = sum;
  __syncthreads();
  sum = (wred[0] + wred[1]) + (wred[2] + wred[3]);
  const float inv = 1.0f / sum;
  const float4 o0 = {pp[0] * inv, pp[1] * inv, pp[2] * inv, pp[3] * inv};
  const float4 o1 = {pp[4] * inv, pp[5] * inv, pp[6] * inv, pp[7] * inv};
  *(float4*)(at + t * 8) = o0;
  *(float4*)(at + t * 8 + 4) = o1;
}

// ---------------- context[b][e] = sum_l attn[b][l] * enc[b][l][e] --------
__global__ __launch_bounds__(256) void context_kernel(
    const float* __restrict__ enc, float* __restrict__ out) {
  __shared__ __align__(16) float attnS[2048];
  __shared__ __align__(16) float red[8 * 128];
  const int bid = blockIdx.x;
  const int b = bid >> 3, ec = bid & 7;
  const int e0 = ec * 128;
  const int t = threadIdx.x;
  const float* attn = out + 32768 + (size_t)b * 2048;
#pragma unroll
  for (int i = 0; i < 8; ++i) attnS[i * 256 + t] = attn[i * 256 + t];
  __syncthreads();
  const int el = (t & 31) * 4;
  const int ls = t >> 5;
  f32x4 acc = {0.f, 0.f, 0.f, 0.f};
  const float* ebase = enc + (size_t)b * 2048 * 1024 + e0 + el;
  for (int l2 = ls; l2 < 2048; l2 += 8) {
    const float a = attnS[l2];
    const float4 ev = *(const float4*)(ebase + (size_t)l2 * 1024);
    acc[0] = fmaf(a, ev.x, acc[0]);
    acc[1] = fmaf(a, ev.y, acc[1]);
    acc[2] = fmaf(a, ev.z, acc[2]);
    acc[3] = fmaf(a, ev.w, acc[3]);
  }
  *(f32x4*)(red + ls * 128 + el) = acc;
  __syncthreads();
  if (t < 128) {
    float s = 0.f;
#pragma unroll
    for (int i = 0; i < 8; ++i) s += red[i * 128 + t];
    out[(size_t)b * 1024 + e0 + t] = s;
  }
}

extern "C" void kernel_launch(void* const* d_in, const int* in_sizes, int n_in,
                              void* d_out, int out_size, void* d_ws,
                              size_t ws_size, hipStream_t stream) {
  const float* enc = (const float*)d_in[0];
  const float* dec = (const float*)d_in[1];
  const int* mask = (const int*)d_in[2];
  const float* W1 = (const float*)d_in[3];
  const float* W2 = (const float*)d_in[4];
  const float* v = (const float*)d_in[5];
  float* out = (float*)d_out;
  char* ws = (char*)d_ws;
  unsigned short* w1b = (unsigned short*)ws;        /* 2 MB pre-swizzled W1 */
  float* u = (float*)(ws + (2u << 20));             /* 128 KB dec projection */
  float* spart = (float*)(ws + (2u << 20) + (128u << 10)); /* 1 MB partials */

  w1cvt_kernel<<<512, 256, 0, stream>>>(W1, w1b);
  dec_proj_kernel<<<1024, 256, 0, stream>>>(dec, W2, u);
  scores_kernel<<<4096, 512, 0, stream>>>(enc, w1b, u, v, spart);
  softmax_kernel<<<32, 256, 0, stream>>>(spart, out, mask);
  context_kernel<<<256, 256, 0, stream>>>(enc, out);
}

// Round 11
// 384.050 us; speedup vs baseline: 1.1013x; 1.1013x over previous
//
#include <hip/hip_runtime.h>
#include <stdint.h>

typedef __bf16 bf16x8 __attribute__((ext_vector_type(8)));
typedef float f32x4 __attribute__((ext_vector_type(4)));
typedef unsigned short ushort8v __attribute__((ext_vector_type(8)));

__device__ __forceinline__ void gload_lds16(const void* g, void* l) {
  __builtin_amdgcn_global_load_lds(
      (const __attribute__((address_space(1))) void*)g,
      (__attribute__((address_space(3))) void*)l, 16, 0, 0);
}

__device__ __forceinline__ unsigned short f2bf(float f) {
  union { float f; unsigned int u; } x; x.f = f;
  unsigned int r = x.u + 0x7FFFu + ((x.u >> 16) & 1u);
  return (unsigned short)(r >> 16);
}

__device__ __forceinline__ float ftanh(float x) {
  float ax = fabsf(x);
  float e = __expf(-2.0f * ax);
  float r = (1.0f - e) / (1.0f + e);
  return copysignf(r, x);
}

// -------- W1 f32 -> bf16, PRE-SWIZZLED 16 KB chunk layout --------
// chunk p = (hh*8 + k8)*8 + c8 covers a in [hh*512 + c8*64, +64),
// k in [k8*128, +128). Within a chunk (64 rows x 256 B), dest byte d
// holds source k-byte (d&255) ^ ((row&15)<<4), row = d>>8 (inverse of
// the read swizzle): LINEAR global->LDS copy + swizzled read works.
__global__ __launch_bounds__(256) void w1cvt_kernel(
    const float* __restrict__ W1, unsigned short* __restrict__ w1b) {
  const int g = blockIdx.x * 256 + threadIdx.x; /* 16-B piece id */
  const int p = g >> 10;
  const int q = g & 1023;
  const int row = q >> 4;
  const int off = (q & 15) * 16;
  const int srcoff = off ^ ((row & 15) << 4);
  const int c8 = p & 7, k8 = (p >> 3) & 7, hh = p >> 6;
  const int a = hh * 512 + c8 * 64 + row;
  const int k = k8 * 128 + (srcoff >> 1);
  const float* src = W1 + (size_t)a * 1024 + k;
  const float4 v0 = *(const float4*)src;
  const float4 v1 = *(const float4*)(src + 4);
  ushort8v o;
  o[0] = f2bf(v0.x); o[1] = f2bf(v0.y); o[2] = f2bf(v0.z); o[3] = f2bf(v0.w);
  o[4] = f2bf(v1.x); o[5] = f2bf(v1.y); o[6] = f2bf(v1.z); o[7] = f2bf(v1.w);
  *((ushort8v*)w1b + g) = o;
}

// ---------------- u[b][a] = sum_d dec[b][d] * W2[a][d] ----------------
__global__ __launch_bounds__(256) void dec_proj_kernel(
    const float* __restrict__ dec, const float* __restrict__ W2,
    float* __restrict__ u) {
  __shared__ __align__(16) float w2s[1024];
  const int a = blockIdx.x;
  const int t = threadIdx.x;
  *(float4*)(w2s + t * 4) = *(const float4*)(W2 + (size_t)a * 1024 + t * 4);
  __syncthreads();
  const int wid = t >> 6, l = t & 63;
  for (int bi = 0; bi < 8; ++bi) {
    const int b = wid * 8 + bi;
    const float* dp = dec + (size_t)b * 1024;
    float acc = 0.f;
#pragma unroll
    for (int i = 0; i < 4; ++i) {
      const int k = i * 256 + l * 4;
      const float4 dv = *(const float4*)(dp + k);
      const float4 wv = *(const float4*)(w2s + k);
      acc = fmaf(dv.x, wv.x, acc); acc = fmaf(dv.y, wv.y, acc);
      acc = fmaf(dv.z, wv.z, acc); acc = fmaf(dv.w, wv.w, acc);
    }
#pragma unroll
    for (int m = 1; m < 64; m <<= 1) acc += __shfl_xor(acc, m, 64);
    if (l == 0) u[(size_t)b * 1024 + a] = acc;
  }
}

// ---------------- fused scores: v . tanh(enc@W1^T + u) ----------------
// grid 512 (128 rows each), 1024 threads = 16 waves (4 wr x 4 wc).
// M=128: each B chunk serves 2x the MFMAs of R9 -> per-CU phase count
// halves (512->256 slots). Per phase per wave: 4 B-reads + 8 MFMA
// (+8 A-reads amortized per k8 into af regs). B: 16 KB chunks, 3-buf,
// counted vmcnt(1), stages 2 ahead via global_load_lds (pre-swizzled w1b).
// enc: 128x128k bf16 tile (32 KB), VALU-staged per k8 (syncthreads drain).
// LDS 80 KB exactly; sred overlays encL. acc[8][2]=64 AGPR + ~60 VGPR.
__global__ __launch_bounds__(1024, 4) void scores_kernel(
    const float* __restrict__ enc, const unsigned short* __restrict__ w1b,
    const float* __restrict__ u, const float* __restrict__ vvec,
    float* __restrict__ out) {
  __shared__ __align__(16) char encL[32768];
  __shared__ __align__(16) char Bl[49152];

  const int t = threadIdx.x;
  const int bid = blockIdx.x;
  const int m0 = bid * 128;
  const int b = bid >> 4; /* 16 row-tiles per batch (2048/128) */
  const int l = t & 63, wid = t >> 6;
  const int wr = wid >> 2, wc = wid & 3;
  const int lm = l & 15, lg = l >> 4;

  const int row_a0 = wr * 32 + lm; /* rowfrag1 = +16: same (row&15) bits */
  const int aswz = lm << 4;
  const int abase0 = row_a0 * 256;        /* enc row stride 256 B */
  const int bbase = (wc * 16 + lm) * 256; /* B row stride 256 B */
  const int bswz = lm << 4;
  const char* w1c = (const char*)w1b;
  const float* ub = u + (size_t)b * 1024;

  const int sbase = wid * 1024; /* 16 waves x 1 KB = 16 KB chunk */
  const int glane = l * 16;

  f32x4 rowp0 = {0.f, 0.f, 0.f, 0.f}, rowp1 = {0.f, 0.f, 0.f, 0.f};

  // prologue: stage chunk 0 -> buf0, chunk 1 -> buf1 (outstanding = 2)
  gload_lds16(w1c + sbase + glane, Bl + sbase);
  gload_lds16(w1c + 16384 + sbase + glane, Bl + 16384 + sbase);

  const char* nextsrc = w1c + 2 * 16384; /* chunk p+2 source, wraps */
  int bsel = 0; /* current buf = p%3 */
  int nb = 2;   /* buf for p+2 */

  for (int hh = 0; hh < 2; ++hh) {
    f32x4 acc[8][2];
#pragma unroll
    for (int c1 = 0; c1 < 8; ++c1)
#pragma unroll
      for (int c2 = 0; c2 < 2; ++c2) acc[c1][c2] = (f32x4){0.f, 0.f, 0.f, 0.f};

    for (int k8 = 0; k8 < 8; ++k8) {
      bf16x8 af[2][4];
#pragma unroll
      for (int c8 = 0; c8 < 8; ++c8) {
        // ---- phase top: own stage(p) retired; all waves aligned ----
        asm volatile("s_waitcnt vmcnt(1)" ::: "memory");
        __builtin_amdgcn_s_barrier();
        // ---- issue stage(p+2) into the third buffer ----
        gload_lds16(nextsrc + sbase + glane, Bl + nb * 16384 + sbase);
        nextsrc += 16384;
        if (nextsrc == w1c + 2097152) nextsrc = w1c; /* tail dummies wrap */
        if (c8 == 0) {
          // ---- stage enc eighth: 128 rows x 128 k, f32 -> bf16 ----
#pragma unroll
          for (int it = 0; it < 2; ++it) {
            const int c = it * 1024 + t;
            const int row = c >> 4;
            const int k0 = (c & 15) * 8;
            const float* g = enc + (size_t)(m0 + row) * 1024 + k8 * 128 + k0;
            const float4 v0 = *(const float4*)g;
            const float4 v1 = *(const float4*)(g + 4);
            ushort8v o;
            o[0] = f2bf(v0.x); o[1] = f2bf(v0.y); o[2] = f2bf(v0.z); o[3] = f2bf(v0.w);
            o[4] = f2bf(v1.x); o[5] = f2bf(v1.y); o[6] = f2bf(v1.z); o[7] = f2bf(v1.w);
            const int dest = row * 256 + ((k0 * 2) ^ ((row & 15) << 4));
            *(ushort8v*)(encL + dest) = o;
          }
          __syncthreads(); /* full drain: encL + landed B stages visible */
          // ---- A-fragments into registers: 8 ds_read_b128 per k8 ----
#pragma unroll
          for (int rf = 0; rf < 2; ++rf)
#pragma unroll
            for (int kk = 0; kk < 4; ++kk)
              af[rf][kk] = *(const bf16x8*)(encL + abase0 + rf * 4096 +
                                            ((kk * 64 + lg * 16) ^ aswz));
        }
        // ---- compute phase p from buf bsel: 4 B-reads + 8 MFMA ----
        const int cbuf = bsel * 16384;
        __builtin_amdgcn_s_setprio(1);
#pragma unroll
        for (int kk = 0; kk < 4; ++kk) {
          const bf16x8 b0 = *(const bf16x8*)(Bl + cbuf + bbase +
                                             ((kk * 64 + lg * 16) ^ bswz));
          acc[c8][0] = __builtin_amdgcn_mfma_f32_16x16x32_bf16(af[0][kk], b0, acc[c8][0], 0, 0, 0);
          acc[c8][1] = __builtin_amdgcn_mfma_f32_16x16x32_bf16(af[1][kk], b0, acc[c8][1], 0, 0, 0);
        }
        __builtin_amdgcn_s_setprio(0);
        bsel = (bsel + 1 == 3) ? 0 : bsel + 1;
        nb = (nb + 1 == 3) ? 0 : nb + 1;
      }
    }

    // half-epilogue: tanh + v-weighted column reduction (registers only)
#pragma unroll
    for (int c8 = 0; c8 < 8; ++c8) {
      const int colA = hh * 512 + c8 * 64 + wc * 16 + lm;
      const float uu = ub[colA], vv = vvec[colA];
#pragma unroll
      for (int j = 0; j < 4; ++j) {
        rowp0[j] += ftanh(acc[c8][0][j] + uu) * vv;
        rowp1[j] += ftanh(acc[c8][1][j] + uu) * vv;
      }
    }
  }

  // reduce over the 16 col-lanes (lm) of each fragment group
#pragma unroll
  for (int m = 1; m < 16; m <<= 1) {
#pragma unroll
    for (int j = 0; j < 4; ++j) {
      rowp0[j] += __shfl_xor(rowp0[j], m, 64);
      rowp1[j] += __shfl_xor(rowp1[j], m, 64);
    }
  }
  __syncthreads(); /* all compute done; encL free -> overlay sred */
  float* sred = (float*)encL; /* 4 wc-groups x 128 rows = 2 KB */
  if (lm == 0) {
#pragma unroll
    for (int j = 0; j < 4; ++j) {
      sred[wc * 128 + wr * 32 + lg * 4 + j] = rowp0[j];
      sred[wc * 128 + wr * 32 + 16 + lg * 4 + j] = rowp1[j];
    }
  }
  __syncthreads();
  if (t < 128) {
    out[32768 + m0 + t] =
        sred[t] + sred[128 + t] + sred[256 + t] + sred[384 + t];
  }
}

// ---------------- masked softmax over L, in place on out[32768..] --------
__global__ __launch_bounds__(256) void softmax_kernel(
    float* __restrict__ out, const int* __restrict__ mask) {
  __shared__ float wred[4];
  const int bidx = blockIdx.x;
  const int t = threadIdx.x;
  float* sc = out + 32768 + (size_t)bidx * 2048;
  const int* mk = mask + (size_t)bidx * 2048;
  const float4 s0 = *(const float4*)(sc + t * 8);
  const float4 s1 = *(const float4*)(sc + t * 8 + 4);
  const int4 q0 = *(const int4*)(mk + t * 8);
  const int4 q1 = *(const int4*)(mk + t * 8 + 4);
  float v[8] = {s0.x, s0.y, s0.z, s0.w, s1.x, s1.y, s1.z, s1.w};
  int q[8] = {q0.x, q0.y, q0.z, q0.w, q1.x, q1.y, q1.z, q1.w};
  float mx = -3.0e38f;
#pragma unroll
  for (int j = 0; j < 8; ++j) if (q[j] != 0) mx = fmaxf(mx, v[j]);
#pragma unroll
  for (int m = 1; m < 64; m <<= 1) mx = fmaxf(mx, __shfl_xor(mx, m, 64));
  if ((t & 63) == 0) wred[t >> 6] = mx;
  __syncthreads();
  mx = fmaxf(fmaxf(wred[0], wred[1]), fmaxf(wred[2], wred[3]));
  __syncthreads();
  float pp[8]; float sum = 0.f;
#pragma unroll
  for (int j = 0; j < 8; ++j) {
    pp[j] = (q[j] != 0) ? __expf(v[j] - mx) : 0.f;
    sum += pp[j];
  }
#pragma unroll
  for (int m = 1; m < 64; m <<= 1) sum += __shfl_xor(sum, m, 64);
  if ((t & 63) == 0) wred[t >> 6] = sum;
  __syncthreads();
  sum = (wred[0] + wred[1]) + (wred[2] + wred[3]);
  const float inv = 1.0f / sum;
  const float4 o0 = {pp[0] * inv, pp[1] * inv, pp[2] * inv, pp[3] * inv};
  const float4 o1 = {pp[4] * inv, pp[5] * inv, pp[6] * inv, pp[7] * inv};
  *(float4*)(sc + t * 8) = o0;
  *(float4*)(sc + t * 8 + 4) = o1;
}

// ---------------- context[b][e] = sum_l attn[b][l] * enc[b][l][e] --------
__global__ __launch_bounds__(256) void context_kernel(
    const float* __restrict__ enc, float* __restrict__ out) {
  __shared__ __align__(16) float attnS[2048];
  __shared__ __align__(16) float red[8 * 128];
  const int bid = blockIdx.x;
  const int b = bid >> 3, ec = bid & 7;
  const int e0 = ec * 128;
  const int t = threadIdx.x;
  const float* attn = out + 32768 + (size_t)b * 2048;
#pragma unroll
  for (int i = 0; i < 8; ++i) attnS[i * 256 + t] = attn[i * 256 + t];
  __syncthreads();
  const int el = (t & 31) * 4;
  const int ls = t >> 5;
  f32x4 acc = {0.f, 0.f, 0.f, 0.f};
  const float* ebase = enc + (size_t)b * 2048 * 1024 + e0 + el;
  for (int l2 = ls; l2 < 2048; l2 += 8) {
    const float a = attnS[l2];
    const float4 ev = *(const float4*)(ebase + (size_t)l2 * 1024);
    acc[0] = fmaf(a, ev.x, acc[0]);
    acc[1] = fmaf(a, ev.y, acc[1]);
    acc[2] = fmaf(a, ev.z, acc[2]);
    acc[3] = fmaf(a, ev.w, acc[3]);
  }
  *(f32x4*)(red + ls * 128 + el) = acc;
  __syncthreads();
  if (t < 128) {
    float s = 0.f;
#pragma unroll
    for (int i = 0; i < 8; ++i) s += red[i * 128 + t];
    out[(size_t)b * 1024 + e0 + t] = s;
  }
}

extern "C" void kernel_launch(void* const* d_in, const int* in_sizes, int n_in,
                              void* d_out, int out_size, void* d_ws,
                              size_t ws_size, hipStream_t stream) {
  const float* enc = (const float*)d_in[0];
  const float* dec = (const float*)d_in[1];
  const int* mask = (const int*)d_in[2];
  const float* W1 = (const float*)d_in[3];
  const float* W2 = (const float*)d_in[4];
  const float* v = (const float*)d_in[5];
  float* out = (float*)d_out;
  char* ws = (char*)d_ws;
  unsigned short* w1b = (unsigned short*)ws; /* 2 MB pre-swizzled bf16 W1 */
  float* u = (float*)(ws + (2u << 20));      /* 128 KB dec projection */

  w1cvt_kernel<<<512, 256, 0, stream>>>(W1, w1b);
  dec_proj_kernel<<<1024, 256, 0, stream>>>(dec, W2, u);
  scores_kernel<<<512, 1024, 0, stream>>>(enc, w1b, u, v, out);
  softmax_kernel<<<32, 256, 0, stream>>>(out, mask);
  context_kernel<<<256, 256, 0, stream>>>(enc, out);
}

// Round 12
// 324.193 us; speedup vs baseline: 1.3047x; 1.1846x over previous
//
#include <hip/hip_runtime.h>
#include <stdint.h>

typedef __bf16 bf16x8 __attribute__((ext_vector_type(8)));
typedef float f32x4 __attribute__((ext_vector_type(4)));
typedef unsigned short ushort8v __attribute__((ext_vector_type(8)));

__device__ __forceinline__ void gload_lds16(const void* g, void* l) {
  __builtin_amdgcn_global_load_lds(
      (const __attribute__((address_space(1))) void*)g,
      (__attribute__((address_space(3))) void*)l, 16, 0, 0);
}

__device__ __forceinline__ unsigned short f2bf(float f) {
  union { float f; unsigned int u; } x; x.f = f;
  unsigned int r = x.u + 0x7FFFu + ((x.u >> 16) & 1u);
  return (unsigned short)(r >> 16);
}

__device__ __forceinline__ float ftanh(float x) {
  float ax = fabsf(x);
  float e = __expf(-2.0f * ax);
  float r = (1.0f - e) / (1.0f + e);
  return copysignf(r, x);
}

// -------- W1 f32 -> bf16, linear 8 KB chunk layout --------
// chunk c = ntile*32 + kstep covers a in [ntile*128,+128), k in
// [kstep*32,+32). Within chunk, byte d: col = d>>6, k = kstep*32+(d&63)/2
// (row-major [col][k], 64 B per col). Linear global->LDS copy works; frag
// reads are contiguous 1 KB per frag -> conflict-free, no swizzle.
__global__ __launch_bounds__(256) void w1cvt_kernel(
    const float* __restrict__ W1, unsigned short* __restrict__ w1b) {
  const int g = blockIdx.x * 256 + threadIdx.x; /* 16-B piece id */
  const int chunk = g >> 9;
  const int dpos = (g & 511) * 16;
  const int ntile = chunk >> 5, kstep = chunk & 31;
  const int col = dpos >> 6;
  const int k0 = (dpos & 63) >> 1;
  const float* src = W1 + (size_t)(ntile * 128 + col) * 1024 + kstep * 32 + k0;
  const float4 v0 = *(const float4*)src;
  const float4 v1 = *(const float4*)(src + 4);
  ushort8v o;
  o[0] = f2bf(v0.x); o[1] = f2bf(v0.y); o[2] = f2bf(v0.z); o[3] = f2bf(v0.w);
  o[4] = f2bf(v1.x); o[5] = f2bf(v1.y); o[6] = f2bf(v1.z); o[7] = f2bf(v1.w);
  *((ushort8v*)w1b + g) = o;
}

// ---------------- u[b][a] = sum_d dec[b][d] * W2[a][d] ----------------
__global__ __launch_bounds__(256) void dec_proj_kernel(
    const float* __restrict__ dec, const float* __restrict__ W2,
    float* __restrict__ u) {
  __shared__ __align__(16) float w2s[1024];
  const int a = blockIdx.x;
  const int t = threadIdx.x;
  *(float4*)(w2s + t * 4) = *(const float4*)(W2 + (size_t)a * 1024 + t * 4);
  __syncthreads();
  const int wid = t >> 6, l = t & 63;
  for (int bi = 0; bi < 8; ++bi) {
    const int b = wid * 8 + bi;
    const float* dp = dec + (size_t)b * 1024;
    float acc = 0.f;
#pragma unroll
    for (int i = 0; i < 4; ++i) {
      const int k = i * 256 + l * 4;
      const float4 dv = *(const float4*)(dp + k);
      const float4 wv = *(const float4*)(w2s + k);
      acc = fmaf(dv.x, wv.x, acc); acc = fmaf(dv.y, wv.y, acc);
      acc = fmaf(dv.z, wv.z, acc); acc = fmaf(dv.w, wv.w, acc);
    }
#pragma unroll
    for (int m = 1; m < 64; m <<= 1) acc += __shfl_xor(acc, m, 64);
    if (l == 0) u[(size_t)b * 1024 + a] = acc;
  }
}

// ------------- fused partial scores: v . tanh(enc@W1^T + u) -------------
// m97-port: 256 thr (4 waves, 2x2), BM=128 BN=128 BK=32, acc[4][4] = 16
// INDEPENDENT MFMAs per K-step per wave (ILP hides MFMA latency).
// A: VALU-staged f32->bf16, dbuf 2x8 KB; B: global_load_lds, dbuf 2x8 KB.
// One __syncthreads per K-step. LDS 34 KB -> 3 blocks/CU at <=170 VGPR.
// XCD mapping: panel = (bid&7)+((bid>>6)<<3), ntile = (bid>>3)&7 -> a
// panel's 8 n-tiles run on one XCD -> enc panel L2-shared, read once.
__global__ __launch_bounds__(256, 3) void scores_kernel(
    const float* __restrict__ enc, const unsigned short* __restrict__ w1b,
    const float* __restrict__ u, const float* __restrict__ vvec,
    float* __restrict__ spart) {
  __shared__ __align__(16) char Al[16384];
  __shared__ __align__(16) char Bl[16384];
  __shared__ __align__(16) float sred[256];

  const int t = threadIdx.x;
  const int bid = blockIdx.x;
  const int panel = (bid & 7) + ((bid >> 6) << 3); /* 0..511 */
  const int ntile = (bid >> 3) & 7;                /* 0..7   */
  const int m0 = panel * 128;
  const int n0 = ntile * 128;
  const int b = panel >> 4; /* 16 panels per batch */
  const int l = t & 63, wid = t >> 6;
  const int wr = wid >> 1, wc = wid & 1;
  const int lm = l & 15, lg = l >> 4;

  const char* w1c = (const char*)w1b + (size_t)ntile * 262144;
  const float* ub = u + (size_t)b * 1024;

  // frag read bases ([row][64B] layout, contiguous per frag)
  const int abase = (wr * 64 + lm) * 64 + lg * 16; /* + mi*1024 */
  const int bbase = (wc * 64 + lm) * 64 + lg * 16; /* + ni*1024 */

  // A staging: thread t handles elems [t*8,+8) and [2048+t*8,+8)
  const int arow0 = t >> 2;            /* rows 0..63  */
  const int ak0 = (t & 3) * 8;         /* k within 32 */
  const float* encA = enc + (size_t)(m0 + arow0) * 1024 + ak0;
  const float* encB = enc + (size_t)(m0 + 64 + arow0) * 1024 + ak0;
  const int adst = t * 16; /* LDS byte; batch1 at +4096 */

  f32x4 acc[4][4];
#pragma unroll
  for (int mi = 0; mi < 4; ++mi)
#pragma unroll
    for (int ni = 0; ni < 4; ++ni) acc[mi][ni] = (f32x4){0.f, 0.f, 0.f, 0.f};

  // ---------- prologue: stage K-step 0 into buf 0 ----------
  gload_lds16(w1c + t * 16, Bl + t * 16);
  gload_lds16(w1c + 4096 + t * 16, Bl + 4096 + t * 16);
  {
    const float4 p0 = *(const float4*)encA;
    const float4 p1 = *(const float4*)(encA + 4);
    const float4 p2 = *(const float4*)encB;
    const float4 p3 = *(const float4*)(encB + 4);
    ushort8v o0, o1;
    o0[0] = f2bf(p0.x); o0[1] = f2bf(p0.y); o0[2] = f2bf(p0.z); o0[3] = f2bf(p0.w);
    o0[4] = f2bf(p1.x); o0[5] = f2bf(p1.y); o0[6] = f2bf(p1.z); o0[7] = f2bf(p1.w);
    o1[0] = f2bf(p2.x); o1[1] = f2bf(p2.y); o1[2] = f2bf(p2.z); o1[3] = f2bf(p2.w);
    o1[4] = f2bf(p3.x); o1[5] = f2bf(p3.y); o1[6] = f2bf(p3.z); o1[7] = f2bf(p3.w);
    *(ushort8v*)(Al + adst) = o0;
    *(ushort8v*)(Al + 4096 + adst) = o1;
  }
  __syncthreads();

#pragma unroll 2
  for (int ks = 0; ks < 32; ++ks) {
    const int buf = (ks & 1) * 8192;
    const int nbuf = buf ^ 8192;
    float4 p0, p1, p2, p3;
    if (ks < 31) {
      // issue next B stage (DMA) + next A f32 loads (latency hides under MFMA)
      const char* wnext = w1c + (size_t)(ks + 1) * 8192;
      gload_lds16(wnext + t * 16, Bl + nbuf + t * 16);
      gload_lds16(wnext + 4096 + t * 16, Bl + nbuf + 4096 + t * 16);
      const float* ea = encA + (ks + 1) * 32;
      const float* eb = encB + (ks + 1) * 32;
      p0 = *(const float4*)ea;
      p1 = *(const float4*)(ea + 4);
      p2 = *(const float4*)eb;
      p3 = *(const float4*)(eb + 4);
    }
    // compute: 4 A-frags + 4 B-frags, 16 independent MFMAs
    bf16x8 af[4], bf[4];
#pragma unroll
    for (int mi = 0; mi < 4; ++mi)
      af[mi] = *(const bf16x8*)(Al + buf + abase + mi * 1024);
#pragma unroll
    for (int ni = 0; ni < 4; ++ni)
      bf[ni] = *(const bf16x8*)(Bl + buf + bbase + ni * 1024);
    __builtin_amdgcn_s_setprio(1);
#pragma unroll
    for (int mi = 0; mi < 4; ++mi)
#pragma unroll
      for (int ni = 0; ni < 4; ++ni)
        acc[mi][ni] = __builtin_amdgcn_mfma_f32_16x16x32_bf16(
            af[mi], bf[ni], acc[mi][ni], 0, 0, 0);
    __builtin_amdgcn_s_setprio(0);
    if (ks < 31) {
      // write-late: convert + store next A tile
      ushort8v o0, o1;
      o0[0] = f2bf(p0.x); o0[1] = f2bf(p0.y); o0[2] = f2bf(p0.z); o0[3] = f2bf(p0.w);
      o0[4] = f2bf(p1.x); o0[5] = f2bf(p1.y); o0[6] = f2bf(p1.z); o0[7] = f2bf(p1.w);
      o1[0] = f2bf(p2.x); o1[1] = f2bf(p2.y); o1[2] = f2bf(p2.z); o1[3] = f2bf(p2.w);
      o1[4] = f2bf(p3.x); o1[5] = f2bf(p3.y); o1[6] = f2bf(p3.z); o1[7] = f2bf(p3.w);
      *(ushort8v*)(Al + nbuf + adst) = o0;
      *(ushort8v*)(Al + nbuf + 4096 + adst) = o1;
    }
    __syncthreads(); /* drains gload + ds_writes; guards dbuf swap */
  }

  // epilogue: tanh + v-weighted column reduction
  float rowp[4][4];
#pragma unroll
  for (int mi = 0; mi < 4; ++mi)
#pragma unroll
    for (int j = 0; j < 4; ++j) rowp[mi][j] = 0.f;
#pragma unroll
  for (int ni = 0; ni < 4; ++ni) {
    const int colA = n0 + wc * 64 + ni * 16 + lm;
    const float uu = ub[colA], vv = vvec[colA];
#pragma unroll
    for (int mi = 0; mi < 4; ++mi)
#pragma unroll
      for (int j = 0; j < 4; ++j)
        rowp[mi][j] += ftanh(acc[mi][ni][j] + uu) * vv;
  }
  // reduce over the 16 col-lanes (lm)
#pragma unroll
  for (int m = 1; m < 16; m <<= 1)
#pragma unroll
    for (int mi = 0; mi < 4; ++mi)
#pragma unroll
      for (int j = 0; j < 4; ++j) rowp[mi][j] += __shfl_xor(rowp[mi][j], m, 64);
  if (lm == 0) {
#pragma unroll
    for (int mi = 0; mi < 4; ++mi)
#pragma unroll
      for (int j = 0; j < 4; ++j)
        sred[wc * 128 + wr * 64 + mi * 16 + lg * 4 + j] = rowp[mi][j];
  }
  __syncthreads();
  if (t < 128) {
    spart[(size_t)ntile * 65536 + m0 + t] = sred[t] + sred[128 + t];
  }
}

// -------- masked softmax over L: sums 8 partials, writes attn ----------
__global__ __launch_bounds__(256) void softmax_kernel(
    const float* __restrict__ spart, float* __restrict__ out,
    const int* __restrict__ mask) {
  __shared__ float wred[4];
  const int bidx = blockIdx.x;
  const int t = threadIdx.x;
  const int r8 = bidx * 2048 + t * 8;
  float* at = out + 32768 + (size_t)bidx * 2048;
  const int* mk = mask + (size_t)bidx * 2048;
  float v[8] = {0.f, 0.f, 0.f, 0.f, 0.f, 0.f, 0.f, 0.f};
#pragma unroll
  for (int nt = 0; nt < 8; ++nt) {
    const float4 s0 = *(const float4*)(spart + (size_t)nt * 65536 + r8);
    const float4 s1 = *(const float4*)(spart + (size_t)nt * 65536 + r8 + 4);
    v[0] += s0.x; v[1] += s0.y; v[2] += s0.z; v[3] += s0.w;
    v[4] += s1.x; v[5] += s1.y; v[6] += s1.z; v[7] += s1.w;
  }
  const int4 q0 = *(const int4*)(mk + t * 8);
  const int4 q1 = *(const int4*)(mk + t * 8 + 4);
  int q[8] = {q0.x, q0.y, q0.z, q0.w, q1.x, q1.y, q1.z, q1.w};
  float mx = -3.0e38f;
#pragma unroll
  for (int j = 0; j < 8; ++j) if (q[j] != 0) mx = fmaxf(mx, v[j]);
#pragma unroll
  for (int m = 1; m < 64; m <<= 1) mx = fmaxf(mx, __shfl_xor(mx, m, 64));
  if ((t & 63) == 0) wred[t >> 6] = mx;
  __syncthreads();
  mx = fmaxf(fmaxf(wred[0], wred[1]), fmaxf(wred[2], wred[3]));
  __syncthreads();
  float pp[8]; float sum = 0.f;
#pragma unroll
  for (int j = 0; j < 8; ++j) {
    pp[j] = (q[j] != 0) ? __expf(v[j] - mx) : 0.f;
    sum += pp[j];
  }
#pragma unroll
  for (int m = 1; m < 64; m <<= 1) sum += __shfl_xor(sum, m, 64);
  if ((t & 63) == 0) wred[t >> 6] = sum;
  __syncthreads();
  sum = (wred[0] + wred[1]) + (wred[2] + wred[3]);
  const float inv = 1.0f / sum;
  const float4 o0 = {pp[0] * inv, pp[1] * inv, pp[2] * inv, pp[3] * inv};
  const float4 o1 = {pp[4] * inv, pp[5] * inv, pp[6] * inv, pp[7] * inv};
  *(float4*)(at + t * 8) = o0;
  *(float4*)(at + t * 8 + 4) = o1;
}

// ---------------- context[b][e] = sum_l attn[b][l] * enc[b][l][e] --------
__global__ __launch_bounds__(256) void context_kernel(
    const float* __restrict__ enc, float* __restrict__ out) {
  __shared__ __align__(16) float attnS[2048];
  __shared__ __align__(16) float red[8 * 128];
  const int bid = blockIdx.x;
  const int b = bid >> 3, ec = bid & 7;
  const int e0 = ec * 128;
  const int t = threadIdx.x;
  const float* attn = out + 32768 + (size_t)b * 2048;
#pragma unroll
  for (int i = 0; i < 8; ++i) attnS[i * 256 + t] = attn[i * 256 + t];
  __syncthreads();
  const int el = (t & 31) * 4;
  const int ls = t >> 5;
  f32x4 acc = {0.f, 0.f, 0.f, 0.f};
  const float* ebase = enc + (size_t)b * 2048 * 1024 + e0 + el;
  for (int l2 = ls; l2 < 2048; l2 += 8) {
    const float a = attnS[l2];
    const float4 ev = *(const float4*)(ebase + (size_t)l2 * 1024);
    acc[0] = fmaf(a, ev.x, acc[0]);
    acc[1] = fmaf(a, ev.y, acc[1]);
    acc[2] = fmaf(a, ev.z, acc[2]);
    acc[3] = fmaf(a, ev.w, acc[3]);
  }
  *(f32x4*)(red + ls * 128 + el) = acc;
  __syncthreads();
  if (t < 128) {
    float s = 0.f;
#pragma unroll
    for (int i = 0; i < 8; ++i) s += red[i * 128 + t];
    out[(size_t)b * 1024 + e0 + t] = s;
  }
}

extern "C" void kernel_launch(void* const* d_in, const int* in_sizes, int n_in,
                              void* d_out, int out_size, void* d_ws,
                              size_t ws_size, hipStream_t stream) {
  const float* enc = (const float*)d_in[0];
  const float* dec = (const float*)d_in[1];
  const int* mask = (const int*)d_in[2];
  const float* W1 = (const float*)d_in[3];
  const float* W2 = (const float*)d_in[4];
  const float* v = (const float*)d_in[5];
  float* out = (float*)d_out;
  char* ws = (char*)d_ws;
  unsigned short* w1b = (unsigned short*)ws;        /* 2 MB bf16 W1 chunks */
  float* u = (float*)(ws + (2u << 20));             /* 128 KB dec proj */
  float* spart = (float*)(ws + (2u << 20) + (128u << 10)); /* 2 MB partials */

  w1cvt_kernel<<<512, 256, 0, stream>>>(W1, w1b);
  dec_proj_kernel<<<1024, 256, 0, stream>>>(dec, W2, u);
  scores_kernel<<<4096, 256, 0, stream>>>(enc, w1b, u, v, spart);
  softmax_kernel<<<32, 256, 0, stream>>>(spart, out, mask);
  context_kernel<<<256, 256, 0, stream>>>(enc, out);
}

// Round 13
// 275.049 us; speedup vs baseline: 1.5378x; 1.1787x over previous
//
#include <hip/hip_runtime.h>
#include <stdint.h>

typedef __bf16 bf16x8 __attribute__((ext_vector_type(8)));
typedef float f32x4 __attribute__((ext_vector_type(4)));
typedef unsigned short ushort8v __attribute__((ext_vector_type(8)));

__device__ __forceinline__ void gload_lds16(const void* g, void* l) {
  __builtin_amdgcn_global_load_lds(
      (const __attribute__((address_space(1))) void*)g,
      (__attribute__((address_space(3))) void*)l, 16, 0, 0);
}

__device__ __forceinline__ unsigned short f2bf(float f) {
  union { float f; unsigned int u; } x; x.f = f;
  unsigned int r = x.u + 0x7FFFu + ((x.u >> 16) & 1u);
  return (unsigned short)(r >> 16);
}

__device__ __forceinline__ float ftanh(float x) {
  float ax = fabsf(x);
  float e = __expf(-2.0f * ax);
  float r = (1.0f - e) / (1.0f + e);
  return copysignf(r, x);
}

// -------- W1 f32 -> bf16, 16 KB chunks, slot-swizzled --------
// chunk c = np*32 + ks covers a in [np*256,+256), k in [ks*32,+32).
// Piece (col, s) at byte col*64 + s*16 holds source k-elems
// [(s ^ ((col>>1)&3))*8, +8)  -> frag reads are 2-way max (free).
__global__ __launch_bounds__(256) void w1cvt_kernel(
    const float* __restrict__ W1, unsigned short* __restrict__ w1b) {
  const int g = blockIdx.x * 256 + threadIdx.x; /* 16-B piece id */
  const int chunk = g >> 10;
  const int d16 = g & 1023;
  const int col = d16 >> 2, s = d16 & 3;
  const int np = chunk >> 5, ks = chunk & 31;
  const float* src = W1 + (size_t)(np * 256 + col) * 1024 + ks * 32 +
                     ((s ^ ((col >> 1) & 3)) * 8);
  const float4 v0 = *(const float4*)src;
  const float4 v1 = *(const float4*)(src + 4);
  ushort8v o;
  o[0] = f2bf(v0.x); o[1] = f2bf(v0.y); o[2] = f2bf(v0.z); o[3] = f2bf(v0.w);
  o[4] = f2bf(v1.x); o[5] = f2bf(v1.y); o[6] = f2bf(v1.z); o[7] = f2bf(v1.w);
  *((ushort8v*)w1b + g) = o;
}

// ---------------- u[b][a] = sum_d dec[b][d] * W2[a][d] ----------------
__global__ __launch_bounds__(256) void dec_proj_kernel(
    const float* __restrict__ dec, const float* __restrict__ W2,
    float* __restrict__ u) {
  __shared__ __align__(16) float w2s[1024];
  const int a = blockIdx.x;
  const int t = threadIdx.x;
  *(float4*)(w2s + t * 4) = *(const float4*)(W2 + (size_t)a * 1024 + t * 4);
  __syncthreads();
  const int wid = t >> 6, l = t & 63;
  for (int bi = 0; bi < 8; ++bi) {
    const int b = wid * 8 + bi;
    const float* dp = dec + (size_t)b * 1024;
    float acc = 0.f;
#pragma unroll
    for (int i = 0; i < 4; ++i) {
      const int k = i * 256 + l * 4;
      const float4 dv = *(const float4*)(dp + k);
      const float4 wv = *(const float4*)(w2s + k);
      acc = fmaf(dv.x, wv.x, acc); acc = fmaf(dv.y, wv.y, acc);
      acc = fmaf(dv.z, wv.z, acc); acc = fmaf(dv.w, wv.w, acc);
    }
#pragma unroll
    for (int m = 1; m < 64; m <<= 1) acc += __shfl_xor(acc, m, 64);
    if (l == 0) u[(size_t)b * 1024 + a] = acc;
  }
}

// ------------- fused partial scores: v . tanh(enc@W1^T + u) -------------
// 256 thr (4 waves: 2 wr x 2 wc), BM=128, BN=256, BK=32.
// Per wave-K-step: 12 frag reads (4 A + 8 B) feed 32 INDEPENDENT MFMAs;
// slot swizzle s^((row>>1)&3) -> 2-way banks max. A VALU-staged
// (issue-early/write-late), B via global_load_lds dbuf. acc[4][8] =
// 128 AGPR + ~70 VGPR -> 2 waves/SIMD, 2 blocks/CU (LDS 49 KB).
// XCD map: panel=(bid&7)+((bid>>5)<<3), np=(bid>>3)&3 -> a panel's 4
// np-blocks share one XCD L2 -> enc panel read from HBM once.
__global__ __launch_bounds__(256, 2) void scores_kernel(
    const float* __restrict__ enc, const unsigned short* __restrict__ w1b,
    const float* __restrict__ u, const float* __restrict__ vvec,
    float* __restrict__ spart) {
  __shared__ __align__(16) char Al[16384];
  __shared__ __align__(16) char Bl[32768];
  __shared__ __align__(16) float sred[256];

  const int t = threadIdx.x;
  const int bid = blockIdx.x;
  const int np = (bid >> 3) & 3;
  const int panel = (bid & 7) + ((bid >> 5) << 3); /* 0..511 */
  const int m0 = panel * 128;
  const int n0 = np * 256;
  const int b = panel >> 4; /* 16 panels per batch */
  const int l = t & 63, wid = t >> 6;
  const int wr = wid >> 1, wc = wid & 1;
  const int lm = l & 15, lg = l >> 4;

  const int soff = (lg ^ ((lm >> 1) & 3)) * 16; /* swizzled k-slot */
  const int abase = (wr * 64 + lm) * 64 + soff;
  const int bbase = (wc * 128 + lm) * 64 + soff;
  const char* w1base = (const char*)w1b + (size_t)(np * 32) * 16384;
  const float* ub = u + (size_t)b * 1024;

  // A staging: thread t handles pieces (row0, s0) and (row0+64, s0)
  const int row0 = t >> 2;
  const int s0 = t & 3;
  const int xo = (s0 ^ ((row0 >> 1) & 3)) * 8;
  const float* srcA = enc + (size_t)(m0 + row0) * 1024 + xo;
  const int adst = t * 16;

  f32x4 acc[4][8];
#pragma unroll
  for (int mi = 0; mi < 4; ++mi)
#pragma unroll
    for (int ni = 0; ni < 8; ++ni) acc[mi][ni] = (f32x4){0.f, 0.f, 0.f, 0.f};

  // ---------- prologue: stage K-step 0 into buf 0 ----------
#pragma unroll
  for (int i = 0; i < 4; ++i)
    gload_lds16(w1base + i * 4096 + t * 16, Bl + i * 4096 + t * 16);
  {
    const float4 p0 = *(const float4*)srcA;
    const float4 p1 = *(const float4*)(srcA + 4);
    const float4 p2 = *(const float4*)(srcA + 65536);
    const float4 p3 = *(const float4*)(srcA + 65540);
    ushort8v o0, o1;
    o0[0] = f2bf(p0.x); o0[1] = f2bf(p0.y); o0[2] = f2bf(p0.z); o0[3] = f2bf(p0.w);
    o0[4] = f2bf(p1.x); o0[5] = f2bf(p1.y); o0[6] = f2bf(p1.z); o0[7] = f2bf(p1.w);
    o1[0] = f2bf(p2.x); o1[1] = f2bf(p2.y); o1[2] = f2bf(p2.z); o1[3] = f2bf(p2.w);
    o1[4] = f2bf(p3.x); o1[5] = f2bf(p3.y); o1[6] = f2bf(p3.z); o1[7] = f2bf(p3.w);
    *(ushort8v*)(Al + adst) = o0;
    *(ushort8v*)(Al + 4096 + adst) = o1;
  }
  __syncthreads();

#pragma unroll 2
  for (int ks = 0; ks < 32; ++ks) {
    const int abuf = (ks & 1) * 8192;
    const int bbuf = (ks & 1) * 16384;
    float4 p0, p1, p2, p3;
    if (ks < 31) {
      const char* wn = w1base + (size_t)(ks + 1) * 16384;
#pragma unroll
      for (int i = 0; i < 4; ++i)
        gload_lds16(wn + i * 4096 + t * 16,
                    Bl + (bbuf ^ 16384) + i * 4096 + t * 16);
      const float* sa = srcA + (ks + 1) * 32;
      p0 = *(const float4*)sa;
      p1 = *(const float4*)(sa + 4);
      p2 = *(const float4*)(sa + 65536);
      p3 = *(const float4*)(sa + 65540);
    }
    bf16x8 af[4], bf[8];
#pragma unroll
    for (int mi = 0; mi < 4; ++mi)
      af[mi] = *(const bf16x8*)(Al + abuf + abase + mi * 1024);
#pragma unroll
    for (int ni = 0; ni < 8; ++ni)
      bf[ni] = *(const bf16x8*)(Bl + bbuf + bbase + ni * 1024);
    __builtin_amdgcn_s_setprio(1);
#pragma unroll
    for (int mi = 0; mi < 4; ++mi)
#pragma unroll
      for (int ni = 0; ni < 8; ++ni)
        acc[mi][ni] = __builtin_amdgcn_mfma_f32_16x16x32_bf16(
            af[mi], bf[ni], acc[mi][ni], 0, 0, 0);
    __builtin_amdgcn_s_setprio(0);
    if (ks < 31) {
      ushort8v o0, o1;
      o0[0] = f2bf(p0.x); o0[1] = f2bf(p0.y); o0[2] = f2bf(p0.z); o0[3] = f2bf(p0.w);
      o0[4] = f2bf(p1.x); o0[5] = f2bf(p1.y); o0[6] = f2bf(p1.z); o0[7] = f2bf(p1.w);
      o1[0] = f2bf(p2.x); o1[1] = f2bf(p2.y); o1[2] = f2bf(p2.z); o1[3] = f2bf(p2.w);
      o1[4] = f2bf(p3.x); o1[5] = f2bf(p3.y); o1[6] = f2bf(p3.z); o1[7] = f2bf(p3.w);
      *(ushort8v*)(Al + (abuf ^ 8192) + adst) = o0;
      *(ushort8v*)(Al + (abuf ^ 8192) + 4096 + adst) = o1;
    }
    __syncthreads(); /* drains gload + ds_writes; guards dbuf swap */
  }

  // epilogue: tanh + v-weighted column reduction
  float rowp[4][4];
#pragma unroll
  for (int mi = 0; mi < 4; ++mi)
#pragma unroll
    for (int j = 0; j < 4; ++j) rowp[mi][j] = 0.f;
#pragma unroll
  for (int ni = 0; ni < 8; ++ni) {
    const int colA = n0 + wc * 128 + ni * 16 + lm;
    const float uu = ub[colA], vv = vvec[colA];
#pragma unroll
    for (int mi = 0; mi < 4; ++mi)
#pragma unroll
      for (int j = 0; j < 4; ++j)
        rowp[mi][j] += ftanh(acc[mi][ni][j] + uu) * vv;
  }
#pragma unroll
  for (int m = 1; m < 16; m <<= 1)
#pragma unroll
    for (int mi = 0; mi < 4; ++mi)
#pragma unroll
      for (int j = 0; j < 4; ++j) rowp[mi][j] += __shfl_xor(rowp[mi][j], m, 64);
  if (lm == 0) {
#pragma unroll
    for (int mi = 0; mi < 4; ++mi)
#pragma unroll
      for (int j = 0; j < 4; ++j)
        sred[wc * 128 + wr * 64 + mi * 16 + lg * 4 + j] = rowp[mi][j];
  }
  __syncthreads();
  if (t < 128) {
    spart[(size_t)np * 65536 + m0 + t] = sred[t] + sred[128 + t];
  }
}

// -------- masked softmax over L: sums 4 partials, writes attn ----------
__global__ __launch_bounds__(256) void softmax_kernel(
    const float* __restrict__ spart, float* __restrict__ out,
    const int* __restrict__ mask) {
  __shared__ float wred[4];
  const int bidx = blockIdx.x;
  const int t = threadIdx.x;
  const int r8 = bidx * 2048 + t * 8;
  float* at = out + 32768 + (size_t)bidx * 2048;
  const int* mk = mask + (size_t)bidx * 2048;
  float v[8] = {0.f, 0.f, 0.f, 0.f, 0.f, 0.f, 0.f, 0.f};
#pragma unroll
  for (int np = 0; np < 4; ++np) {
    const float4 s0 = *(const float4*)(spart + (size_t)np * 65536 + r8);
    const float4 s1 = *(const float4*)(spart + (size_t)np * 65536 + r8 + 4);
    v[0] += s0.x; v[1] += s0.y; v[2] += s0.z; v[3] += s0.w;
    v[4] += s1.x; v[5] += s1.y; v[6] += s1.z; v[7] += s1.w;
  }
  const int4 q0 = *(const int4*)(mk + t * 8);
  const int4 q1 = *(const int4*)(mk + t * 8 + 4);
  int q[8] = {q0.x, q0.y, q0.z, q0.w, q1.x, q1.y, q1.z, q1.w};
  float mx = -3.0e38f;
#pragma unroll
  for (int j = 0; j < 8; ++j) if (q[j] != 0) mx = fmaxf(mx, v[j]);
#pragma unroll
  for (int m = 1; m < 64; m <<= 1) mx = fmaxf(mx, __shfl_xor(mx, m, 64));
  if ((t & 63) == 0) wred[t >> 6] = mx;
  __syncthreads();
  mx = fmaxf(fmaxf(wred[0], wred[1]), fmaxf(wred[2], wred[3]));
  __syncthreads();
  float pp[8]; float sum = 0.f;
#pragma unroll
  for (int j = 0; j < 8; ++j) {
    pp[j] = (q[j] != 0) ? __expf(v[j] - mx) : 0.f;
    sum += pp[j];
  }
#pragma unroll
  for (int m = 1; m < 64; m <<= 1) sum += __shfl_xor(sum, m, 64);
  if ((t & 63) == 0) wred[t >> 6] = sum;
  __syncthreads();
  sum = (wred[0] + wred[1]) + (wred[2] + wred[3]);
  const float inv = 1.0f / sum;
  const float4 o0 = {pp[0] * inv, pp[1] * inv, pp[2] * inv, pp[3] * inv};
  const float4 o1 = {pp[4] * inv, pp[5] * inv, pp[6] * inv, pp[7] * inv};
  *(float4*)(at + t * 8) = o0;
  *(float4*)(at + t * 8 + 4) = o1;
}

// ---------------- context[b][e] = sum_l attn[b][l] * enc[b][l][e] --------
__global__ __launch_bounds__(256) void context_kernel(
    const float* __restrict__ enc, float* __restrict__ out) {
  __shared__ __align__(16) float attnS[2048];
  __shared__ __align__(16) float red[8 * 128];
  const int bid = blockIdx.x;
  const int b = bid >> 3, ec = bid & 7;
  const int e0 = ec * 128;
  const int t = threadIdx.x;
  const float* attn = out + 32768 + (size_t)b * 2048;
#pragma unroll
  for (int i = 0; i < 8; ++i) attnS[i * 256 + t] = attn[i * 256 + t];
  __syncthreads();
  const int el = (t & 31) * 4;
  const int ls = t >> 5;
  f32x4 acc = {0.f, 0.f, 0.f, 0.f};
  const float* ebase = enc + (size_t)b * 2048 * 1024 + e0 + el;
  for (int l2 = ls; l2 < 2048; l2 += 8) {
    const float a = attnS[l2];
    const float4 ev = *(const float4*)(ebase + (size_t)l2 * 1024);
    acc[0] = fmaf(a, ev.x, acc[0]);
    acc[1] = fmaf(a, ev.y, acc[1]);
    acc[2] = fmaf(a, ev.z, acc[2]);
    acc[3] = fmaf(a, ev.w, acc[3]);
  }
  *(f32x4*)(red + ls * 128 + el) = acc;
  __syncthreads();
  if (t < 128) {
    float s = 0.f;
#pragma unroll
    for (int i = 0; i < 8; ++i) s += red[i * 128 + t];
    out[(size_t)b * 1024 + e0 + t] = s;
  }
}

extern "C" void kernel_launch(void* const* d_in, const int* in_sizes, int n_in,
                              void* d_out, int out_size, void* d_ws,
                              size_t ws_size, hipStream_t stream) {
  const float* enc = (const float*)d_in[0];
  const float* dec = (const float*)d_in[1];
  const int* mask = (const int*)d_in[2];
  const float* W1 = (const float*)d_in[3];
  const float* W2 = (const float*)d_in[4];
  const float* v = (const float*)d_in[5];
  float* out = (float*)d_out;
  char* ws = (char*)d_ws;
  unsigned short* w1b = (unsigned short*)ws;        /* 2 MB bf16 W1 chunks */
  float* u = (float*)(ws + (2u << 20));             /* 128 KB dec proj */
  float* spart = (float*)(ws + (2u << 20) + (128u << 10)); /* 1 MB partials */

  w1cvt_kernel<<<512, 256, 0, stream>>>(W1, w1b);
  dec_proj_kernel<<<1024, 256, 0, stream>>>(dec, W2, u);
  scores_kernel<<<2048, 256, 0, stream>>>(enc, w1b, u, v, spart);
  softmax_kernel<<<32, 256, 0, stream>>>(spart, out, mask);
  context_kernel<<<256, 256, 0, stream>>>(enc, out);
}